// Round 1
// 134.324 us; speedup vs baseline: 1.0756x; 1.0756x over previous
//
#include <hip/hip_runtime.h>

static constexpr int C    = 64;
static constexpr int H    = 128;
static constexpr int W    = 128;
static constexpr int NPIX = H * W;      // 16384
static constexpr int PAD  = 3;          // WS=7 -> +-3

// ---------------------------------------------------------------------------
// 1) conv1x1. Each wave: 64 pixels x 8 output channels. launch_bounds(256,4)
//    gives a 128-VGPR budget so xr[64] stays resident: the FMA body is pure
//    register work (512 fmac) instead of a serialized load->16fmac chain
//    (previous build: VGPR_Count=44 proved the x loads were sunk into the
//    loop). grid (NPIX/64, 2, 3) = 1536 blocks -> 6 blocks/CU.
// ---------------------------------------------------------------------------
__global__ __launch_bounds__(256, 4) void k_conv(
    const float* __restrict__ x,
    const float* __restrict__ Wq, const float* __restrict__ bq,
    const float* __restrict__ Wk, const float* __restrict__ bk,
    const float* __restrict__ Wv, const float* __restrict__ bv,
    float* __restrict__ qT, float* __restrict__ ko, float* __restrict__ vo)
{
    const int tid  = threadIdx.x;
    const int lane = tid & 63;
    const int p    = blockIdx.x * 64 + lane;
    const int o0   = __builtin_amdgcn_readfirstlane(
                         blockIdx.y * 32 + (tid >> 6) * 8);
    const int z    = blockIdx.z;
    const float* Wm = (z == 0) ? Wq : (z == 1) ? Wk : Wv;
    const float* bm = (z == 0) ? bq : (z == 1) ? bk : bv;

    float xr[C];
#pragma unroll
    for (int c = 0; c < C; ++c) xr[c] = x[c * NPIX + p];

    float acc[8];
#pragma unroll
    for (int j = 0; j < 8; ++j) acc[j] = bm[o0 + j];

#pragma unroll
    for (int c = 0; c < C; ++c) {
        const float xv = xr[c];
#pragma unroll
        for (int j = 0; j < 8; ++j)
            acc[j] += Wm[(o0 + j) * C + c] * xv;
    }

    if (z == 0) {
        *(float4*)(qT + (size_t)p * C + o0) =
            make_float4(acc[0], acc[1], acc[2], acc[3]);
        *(float4*)(qT + (size_t)p * C + o0 + 4) =
            make_float4(acc[4], acc[5], acc[6], acc[7]);
    } else {
        float* outm = (z == 1) ? ko : vo;
#pragma unroll
        for (int j = 0; j < 8; ++j)
            outm[(o0 + j) * NPIX + p] = acc[j];
    }
}

// ---------------------------------------------------------------------------
// 2) merged dispatch: [gram+diag] (blocks 0..1023) and [7x7 box of v]
//    (blocks 1024..1535). Gram half now stages the 22 q-rows into LDS once
//    (coalesced, zero-filled at the w-borders) and the j-loop reads them as
//    broadcast ds_read_b128 -- removes the per-iteration dependent s_load
//    chain and the wave-uniform bounds branch. block 256.
// ---------------------------------------------------------------------------
__global__ __launch_bounds__(256, 4) void k_mid(
    const float* __restrict__ qT, const float* __restrict__ kmat,
    const float* __restrict__ v,
    float* __restrict__ Sd, float* __restrict__ Vs)
{
    __shared__ union {
        struct { float Sl[22][130]; float qs[22][64]; } g;   // 16.7 KB
        struct { float vt[22][128]; float vh[22][128]; } box; // 22.5 KB
    } u;
    const int bid = blockIdx.x;
    const int tid = threadIdx.x;

    if (bid < 1024) {
        // ----- fused row-Gram + diagonal 7-sum -----
        const int h   = bid >> 3;
        const int w0  = (bid & 7) * 16;
        const int kk  = tid & 127;
        const int wsl = tid >> 7;            // 0/1, wave-uniform

        // stage q rows w0-3 .. w0+18 (zero-filled outside [0,W))
        for (int i = tid; i < 22 * 16; i += 256) {
            int r  = i >> 4, c4 = (i & 15) << 2;
            int wp = w0 - 3 + r;
            float4 qv = make_float4(0.f, 0.f, 0.f, 0.f);
            if (wp >= 0 && wp < W)
                qv = *(const float4*)(qT + (size_t)(h * W + wp) * C + c4);
            *(float4*)(&u.g.qs[r][c4]) = qv;
        }

        float ksr[C];
#pragma unroll
        for (int c = 0; c < C; ++c) ksr[c] = kmat[c * NPIX + h * W + kk];
        __syncthreads();

        for (int j = 0; j < 11; ++j) {
            int row = wsl * 11 + j;          // 0..21, wave-uniform
            float a0 = 0.f, a1 = 0.f, a2 = 0.f, a3 = 0.f;
#pragma unroll
            for (int c = 0; c < C; c += 4) {
                float4 qv = *(const float4*)(&u.g.qs[row][c]); // broadcast
                a0 += qv.x * ksr[c + 0];
                a1 += qv.y * ksr[c + 1];
                a2 += qv.z * ksr[c + 2];
                a3 += qv.w * ksr[c + 3];
            }
            u.g.Sl[row][kk] = (a0 + a1) + (a2 + a3);
        }
        __syncthreads();

#pragma unroll
        for (int r = 0; r < 8; ++r) {
            int wl = wsl * 8 + r;            // 0..15
            float a = 0.f;
#pragma unroll
            for (int dd = -PAD; dd <= PAD; ++dd) {
                int kj = kk + dd;
                if (kj >= 0 && kj < W)
                    a += u.g.Sl[wl + 3 + dd][kj];
            }
            Sd[(size_t)(h * W + w0 + wl) * W + kk] = a;
        }
    } else {
        // ----- 7x7 box sum of v (separable in LDS) -----
        const int b2 = bid - 1024;           // 0..511
        const int c  = b2 >> 3;              // 0..63
        const int h0 = (b2 & 7) * 16;

        for (int i = tid; i < 22 * 128; i += 256) {
            int r = i >> 7, w = i & 127;
            int h = h0 - 3 + r;
            u.box.vt[r][w] = (h >= 0 && h < H) ? v[c * NPIX + h * W + w] : 0.f;
        }
        __syncthreads();
        for (int i = tid; i < 22 * 128; i += 256) {
            int r = i >> 7, w = i & 127;
            float s = 0.f;
#pragma unroll
            for (int d = -PAD; d <= PAD; ++d) {
                int wj = w + d;
                if (wj >= 0 && wj < W) s += u.box.vt[r][wj];
            }
            u.box.vh[r][w] = s;
        }
        __syncthreads();
        for (int i = tid; i < 16 * 128; i += 256) {
            int r = i >> 7, w = i & 127;
            float s = 0.f;
#pragma unroll
            for (int d = 0; d < 7; ++d) s += u.box.vh[r + d][w];
            Vs[c * NPIX + (h0 + r) * W + w] = s;
        }
    }
}

// ---------------------------------------------------------------------------
// 3) vertical 7-sum of Sd + softmax, h-tiled: block = (w, 16-h tile).
//    Sd rows h0-3..h0+18 staged in LDS (22x132 pad -> conflict-free), then
//    16 lanes per h (8 kk each, stride 16), 16-lane shuffle softmax.
//    grid (W, H/16), block 256.   [unchanged this round]
// ---------------------------------------------------------------------------
__global__ __launch_bounds__(256) void k_softmax(
    const float* __restrict__ Sd, float* __restrict__ attn)
{
    __shared__ float Sl[22][132];    // 11.6 KB
    const int w   = blockIdx.x;
    const int h0  = blockIdx.y * 16;
    const int tid = threadIdx.x;

    for (int i = tid; i < 22 * 128; i += 256) {
        int r = i >> 7, kk = i & 127;
        int h = h0 - 3 + r;
        Sl[r][kk] = (h >= 0 && h < H)
                  ? Sd[(size_t)h * NPIX + w * W + kk] : 0.f;
    }
    __syncthreads();

    const int hl  = tid >> 4;        // 0..15 (h within tile)
    const int sub = tid & 15;        // kk % 16

    float lg[8];
#pragma unroll
    for (int r = 0; r < 8; ++r) {
        int kk = sub + 16 * r;
        float a = 0.f;
#pragma unroll
        for (int d = 0; d < 7; ++d) a += Sl[hl + d][kk];
        lg[r] = a;
    }

    float m = lg[0];
#pragma unroll
    for (int r = 1; r < 8; ++r) m = fmaxf(m, lg[r]);
#pragma unroll
    for (int off = 1; off <= 8; off <<= 1) m = fmaxf(m, __shfl_xor(m, off));
    float ssum = 0.f;
#pragma unroll
    for (int r = 0; r < 8; ++r) { lg[r] = __expf(lg[r] - m); ssum += lg[r]; }
#pragma unroll
    for (int off = 1; off <= 8; off <<= 1) ssum += __shfl_xor(ssum, off);
    float inv = 1.f / ssum;

    float* arow = attn + (size_t)(h0 + hl) * NPIX + (size_t)w * W;
#pragma unroll
    for (int r = 0; r < 8; ++r) arow[sub + 16 * r] = lg[r] * inv;
}

// ---------------------------------------------------------------------------
// 4) out[c,h,w] = sum_kk attn[h,w,kk] * Vs[c,h,kk]  — lanes = w, channels
//    wave-uniform -> Vs via s_load; attn LDS-staged (padded). 8 acc chains.
//    grid (H, 4), block 256.   [unchanged this round]
// ---------------------------------------------------------------------------
__global__ __launch_bounds__(256) void k_out(
    const float* __restrict__ attn, const float* __restrict__ Vs,
    float* __restrict__ out)
{
    __shared__ float As[W][65];      // 33.3 KB
    const int h   = blockIdx.x;
    const int tid = threadIdx.x;
    const int w   = tid & 127;
    const int c0  = __builtin_amdgcn_readfirstlane(
                        blockIdx.y * 16 + (tid >> 7) * 8);
    const int hb  = h * W;

    float acc[8];
#pragma unroll
    for (int j = 0; j < 8; ++j) acc[j] = 0.f;

    for (int kc = 0; kc < W; kc += 64) {
        __syncthreads();
        for (int i = tid; i < W * 64; i += 256) {
            int kk = i & 63, ww = i >> 6;
            As[ww][kk] = attn[(size_t)h * NPIX + ww * W + kc + kk];
        }
        __syncthreads();
#pragma unroll 4
        for (int kk = 0; kk < 64; ++kk) {
            float a = As[w][kk];
#pragma unroll
            for (int j = 0; j < 8; ++j)
                acc[j] += Vs[(size_t)(c0 + j) * NPIX + hb + kc + kk] * a;
        }
    }

#pragma unroll
    for (int j = 0; j < 8; ++j)
        out[(size_t)(c0 + j) * NPIX + hb + w] = acc[j];
}

// ---------------------------------------------------------------------------
// Workspace: 8M floats = 32 MB used, non-overlapping:
//   qT [0,1M)  k [1M,2M)  v [2M,3M)  Sd [3M,5M)  Vs [5M,6M)  attn [6M,8M)
// ---------------------------------------------------------------------------
extern "C" void kernel_launch(void* const* d_in, const int* in_sizes, int n_in,
                              void* d_out, int out_size, void* d_ws, size_t ws_size,
                              hipStream_t stream)
{
    const float* x  = (const float*)d_in[0];
    const float* Wq = (const float*)d_in[1];
    const float* bq = (const float*)d_in[2];
    const float* Wk = (const float*)d_in[3];
    const float* bk = (const float*)d_in[4];
    const float* Wv = (const float*)d_in[5];
    const float* bv = (const float*)d_in[6];
    float* out = (float*)d_out;

    float* ws = (float*)d_ws;
    const size_t NQ = (size_t)C * NPIX;       // 1M floats
    const size_t NS = (size_t)H * W * W;      // 2M floats

    float* qT   = ws;
    float* k    = ws + NQ;
    float* v    = ws + 2 * NQ;
    float* Sd   = ws + 3 * NQ;
    float* Vsum = ws + 3 * NQ + NS;
    float* attn = ws + 4 * NQ + NS;

    k_conv<<<dim3(NPIX / 64, 2, 3), 256, 0, stream>>>(x, Wq, bq, Wk, bk, Wv, bv, qT, k, v);
    k_mid<<<dim3(1536), 256, 0, stream>>>(qT, k, v, Sd, Vsum);
    k_softmax<<<dim3(W, H / 16), 256, 0, stream>>>(Sd, attn);
    k_out<<<dim3(H, 4), 256, 0, stream>>>(attn, Vsum, out);
}

// Round 2
// 124.723 us; speedup vs baseline: 1.1584x; 1.0770x over previous
//
#include <hip/hip_runtime.h>

static constexpr int C    = 64;
static constexpr int H    = 128;
static constexpr int W    = 128;
static constexpr int NPIX = H * W;      // 16384
static constexpr int PAD  = 3;          // WS=7 -> +-3

// ---------------------------------------------------------------------------
// 1) conv1x1. Each wave: 64 pixels x 8 output channels. launch_bounds(256,4)
//    gives a 128-VGPR budget so xr[64] stays resident: pure register FMA body.
//    grid (NPIX/64, 2, 3) = 1536 blocks -> 6 blocks/CU.   [unchanged]
// ---------------------------------------------------------------------------
__global__ __launch_bounds__(256, 4) void k_conv(
    const float* __restrict__ x,
    const float* __restrict__ Wq, const float* __restrict__ bq,
    const float* __restrict__ Wk, const float* __restrict__ bk,
    const float* __restrict__ Wv, const float* __restrict__ bv,
    float* __restrict__ qT, float* __restrict__ ko, float* __restrict__ vo)
{
    const int tid  = threadIdx.x;
    const int lane = tid & 63;
    const int p    = blockIdx.x * 64 + lane;
    const int o0   = __builtin_amdgcn_readfirstlane(
                         blockIdx.y * 32 + (tid >> 6) * 8);
    const int z    = blockIdx.z;
    const float* Wm = (z == 0) ? Wq : (z == 1) ? Wk : Wv;
    const float* bm = (z == 0) ? bq : (z == 1) ? bk : bv;

    float xr[C];
#pragma unroll
    for (int c = 0; c < C; ++c) xr[c] = x[c * NPIX + p];

    float acc[8];
#pragma unroll
    for (int j = 0; j < 8; ++j) acc[j] = bm[o0 + j];

#pragma unroll
    for (int c = 0; c < C; ++c) {
        const float xv = xr[c];
#pragma unroll
        for (int j = 0; j < 8; ++j)
            acc[j] += Wm[(o0 + j) * C + c] * xv;
    }

    if (z == 0) {
        *(float4*)(qT + (size_t)p * C + o0) =
            make_float4(acc[0], acc[1], acc[2], acc[3]);
        *(float4*)(qT + (size_t)p * C + o0 + 4) =
            make_float4(acc[4], acc[5], acc[6], acc[7]);
    } else {
        float* outm = (z == 1) ? ko : vo;
#pragma unroll
        for (int j = 0; j < 8; ++j)
            outm[(o0 + j) * NPIX + p] = acc[j];
    }
}

// ---------------------------------------------------------------------------
// 2) merged dispatch: [gram+diag] (blocks 0..1023) and [7x7 box of v]
//    (blocks 1024..1535). block 256.   [unchanged]
// ---------------------------------------------------------------------------
__global__ __launch_bounds__(256, 4) void k_mid(
    const float* __restrict__ qT, const float* __restrict__ kmat,
    const float* __restrict__ v,
    float* __restrict__ Sd, float* __restrict__ Vs)
{
    __shared__ union {
        struct { float Sl[22][130]; float qs[22][64]; } g;   // 16.7 KB
        struct { float vt[22][128]; float vh[22][128]; } box; // 22.5 KB
    } u;
    const int bid = blockIdx.x;
    const int tid = threadIdx.x;

    if (bid < 1024) {
        // ----- fused row-Gram + diagonal 7-sum -----
        const int h   = bid >> 3;
        const int w0  = (bid & 7) * 16;
        const int kk  = tid & 127;
        const int wsl = tid >> 7;            // 0/1, wave-uniform

        // stage q rows w0-3 .. w0+18 (zero-filled outside [0,W))
        for (int i = tid; i < 22 * 16; i += 256) {
            int r  = i >> 4, c4 = (i & 15) << 2;
            int wp = w0 - 3 + r;
            float4 qv = make_float4(0.f, 0.f, 0.f, 0.f);
            if (wp >= 0 && wp < W)
                qv = *(const float4*)(qT + (size_t)(h * W + wp) * C + c4);
            *(float4*)(&u.g.qs[r][c4]) = qv;
        }

        float ksr[C];
#pragma unroll
        for (int c = 0; c < C; ++c) ksr[c] = kmat[c * NPIX + h * W + kk];
        __syncthreads();

        for (int j = 0; j < 11; ++j) {
            int row = wsl * 11 + j;          // 0..21, wave-uniform
            float a0 = 0.f, a1 = 0.f, a2 = 0.f, a3 = 0.f;
#pragma unroll
            for (int c = 0; c < C; c += 4) {
                float4 qv = *(const float4*)(&u.g.qs[row][c]); // broadcast
                a0 += qv.x * ksr[c + 0];
                a1 += qv.y * ksr[c + 1];
                a2 += qv.z * ksr[c + 2];
                a3 += qv.w * ksr[c + 3];
            }
            u.g.Sl[row][kk] = (a0 + a1) + (a2 + a3);
        }
        __syncthreads();

#pragma unroll
        for (int r = 0; r < 8; ++r) {
            int wl = wsl * 8 + r;            // 0..15
            float a = 0.f;
#pragma unroll
            for (int dd = -PAD; dd <= PAD; ++dd) {
                int kj = kk + dd;
                if (kj >= 0 && kj < W)
                    a += u.g.Sl[wl + 3 + dd][kj];
            }
            Sd[(size_t)(h * W + w0 + wl) * W + kk] = a;
        }
    } else {
        // ----- 7x7 box sum of v (separable in LDS) -----
        const int b2 = bid - 1024;           // 0..511
        const int c  = b2 >> 3;              // 0..63
        const int h0 = (b2 & 7) * 16;

        for (int i = tid; i < 22 * 128; i += 256) {
            int r = i >> 7, w = i & 127;
            int h = h0 - 3 + r;
            u.box.vt[r][w] = (h >= 0 && h < H) ? v[c * NPIX + h * W + w] : 0.f;
        }
        __syncthreads();
        for (int i = tid; i < 22 * 128; i += 256) {
            int r = i >> 7, w = i & 127;
            float s = 0.f;
#pragma unroll
            for (int d = -PAD; d <= PAD; ++d) {
                int wj = w + d;
                if (wj >= 0 && wj < W) s += u.box.vt[r][wj];
            }
            u.box.vh[r][w] = s;
        }
        __syncthreads();
        for (int i = tid; i < 16 * 128; i += 256) {
            int r = i >> 7, w = i & 127;
            float s = 0.f;
#pragma unroll
            for (int d = 0; d < 7; ++d) s += u.box.vh[r + d][w];
            Vs[c * NPIX + (h0 + r) * W + w] = s;
        }
    }
}

// ---------------------------------------------------------------------------
// 3) FUSED vertical-7-sum + softmax + PV contraction. One block per
//    (h, w-half): grid (H, 2) = 256 blocks x 512 threads (2 waves/SIMD,
//    full CU coverage). Phase A: logits straight from Sd (7 rows, L2/L3
//    resident), 8-lane shuffle softmax, attn -> LDS (pitch 129: conflict-
//    free writes, 2-lane/bank reads). Phase B: Vs row staged in LDS (loads
//    issued at kernel start, overlap phase A), 64w x 64c x 128kk contraction
//    with 8 independent FMA chains. Kills the 16 MB attn round-trip and one
//    dispatch barrier; no scalar-load chains.
// ---------------------------------------------------------------------------
__global__ __launch_bounds__(512, 2) void k_fused(
    const float* __restrict__ Sd, const float* __restrict__ Vs,
    float* __restrict__ out)
{
    constexpr int AP = 129;          // attn LDS pitch (odd -> conflict-free)
    __shared__ float At[64][AP];     // attn[w-local][kk], 33.0 KB
    __shared__ float Vl[64][128];    // Vs[c][kk],         32.8 KB -> 65.8 KB

    const int h   = blockIdx.x;
    const int w0  = blockIdx.y * 64;
    const int tid = threadIdx.x;

    // ---- issue Vs staging loads early (consumed after phase A) ----
    float4 vstage[4];
#pragma unroll
    for (int r = 0; r < 4; ++r) {
        int L  = tid + r * 512;          // 0..2047 float4 tiles
        int c  = L >> 5;                 // 32 float4 per channel row
        int k4 = (L & 31) << 2;
        vstage[r] = *(const float4*)(Vs + (size_t)c * NPIX + h * W + k4);
    }

    // ---- phase A: logits + softmax into LDS ----
    const int wl = tid >> 3;             // 0..63 (w within half)
    const int s  = tid & 7;              // kk-octant: kk = s*16 + e

    float4 g0 = make_float4(0.f, 0.f, 0.f, 0.f);
    float4 g1 = g0, g2 = g0, g3 = g0;
#pragma unroll
    for (int i = 0; i < 7; ++i) {
        int hp = h - 3 + i;              // wave-uniform branch
        if (hp >= 0 && hp < H) {
            const float4* src = (const float4*)(
                Sd + (size_t)hp * NPIX + (w0 + wl) * W + s * 16);
            float4 a = src[0], b = src[1], c2 = src[2], d = src[3];
            g0.x += a.x;  g0.y += a.y;  g0.z += a.z;  g0.w += a.w;
            g1.x += b.x;  g1.y += b.y;  g1.z += b.z;  g1.w += b.w;
            g2.x += c2.x; g2.y += c2.y; g2.z += c2.z; g2.w += c2.w;
            g3.x += d.x;  g3.y += d.y;  g3.z += d.z;  g3.w += d.w;
        }
    }

    float lg[16] = { g0.x, g0.y, g0.z, g0.w,  g1.x, g1.y, g1.z, g1.w,
                     g2.x, g2.y, g2.z, g2.w,  g3.x, g3.y, g3.z, g3.w };

    float m = lg[0];
#pragma unroll
    for (int e = 1; e < 16; ++e) m = fmaxf(m, lg[e]);
#pragma unroll
    for (int off = 1; off <= 4; off <<= 1) m = fmaxf(m, __shfl_xor(m, off));

    float ssum = 0.f;
#pragma unroll
    for (int e = 0; e < 16; ++e) { lg[e] = __expf(lg[e] - m); ssum += lg[e]; }
#pragma unroll
    for (int off = 1; off <= 4; off <<= 1) ssum += __shfl_xor(ssum, off);
    const float inv = 1.f / ssum;

#pragma unroll
    for (int e = 0; e < 16; ++e) At[wl][s * 16 + e] = lg[e] * inv;

    // ---- land Vs into LDS, sync ----
#pragma unroll
    for (int r = 0; r < 4; ++r) {
        int L  = tid + r * 512;
        int c  = L >> 5;
        int k4 = (L & 31) << 2;
        *(float4*)(&Vl[c][k4]) = vstage[r];
    }
    __syncthreads();

    // ---- phase B: out[c, h, w0+w2] = sum_kk At[w2][kk] * Vl[c][kk] ----
    const int w2 = tid & 63;
    const int c0 = __builtin_amdgcn_readfirstlane((tid >> 6) * 8);

    float acc[8];
#pragma unroll
    for (int j = 0; j < 8; ++j) acc[j] = 0.f;

    for (int kk = 0; kk < 128; kk += 4) {
        float4 a = *(const float4*)(&At[w2][kk]);
#pragma unroll
        for (int j = 0; j < 8; ++j) {
            float4 vv = *(const float4*)(&Vl[c0 + j][kk]);   // broadcast
            acc[j] += a.x * vv.x + a.y * vv.y + a.z * vv.z + a.w * vv.w;
        }
    }

#pragma unroll
    for (int j = 0; j < 8; ++j)
        out[(size_t)(c0 + j) * NPIX + h * W + w0 + w2] = acc[j];
}

// ---------------------------------------------------------------------------
// Workspace: 6M floats = 24 MB used, non-overlapping:
//   qT [0,1M)  k [1M,2M)  v [2M,3M)  Sd [3M,5M)  Vs [5M,6M)
// ---------------------------------------------------------------------------
extern "C" void kernel_launch(void* const* d_in, const int* in_sizes, int n_in,
                              void* d_out, int out_size, void* d_ws, size_t ws_size,
                              hipStream_t stream)
{
    const float* x  = (const float*)d_in[0];
    const float* Wq = (const float*)d_in[1];
    const float* bq = (const float*)d_in[2];
    const float* Wk = (const float*)d_in[3];
    const float* bk = (const float*)d_in[4];
    const float* Wv = (const float*)d_in[5];
    const float* bv = (const float*)d_in[6];
    float* out = (float*)d_out;

    float* ws = (float*)d_ws;
    const size_t NQ = (size_t)C * NPIX;       // 1M floats
    const size_t NS = (size_t)H * W * W;      // 2M floats

    float* qT   = ws;
    float* k    = ws + NQ;
    float* v    = ws + 2 * NQ;
    float* Sd   = ws + 3 * NQ;
    float* Vsum = ws + 3 * NQ + NS;

    k_conv<<<dim3(NPIX / 64, 2, 3), 256, 0, stream>>>(x, Wq, bq, Wk, bk, Wv, bv, qT, k, v);
    k_mid<<<dim3(1536), 256, 0, stream>>>(qT, k, v, Sd, Vsum);
    k_fused<<<dim3(H, 2), 512, 0, stream>>>(Sd, Vsum, out);
}